// Round 1
// 970.466 us; speedup vs baseline: 1.0107x; 1.0107x over previous
//
#include <hip/hip_runtime.h>
#include <math.h>

#define DIM    768
#define PE     200
#define LSPAN  20
#define NPAIRS 256
#define ROWS   5120
#define EMB    128
#define VOCAB  30522

typedef __attribute__((ext_vector_type(8))) short short8;
typedef __attribute__((ext_vector_type(4))) float floatx4;

__device__ inline unsigned short f2bf(float f) {
    union { float f; unsigned int u; } v; v.f = f;
    unsigned int r = v.u + 0x7fffu + ((v.u >> 16) & 1u);
    return (unsigned short)(r >> 16);
}
__device__ inline float gelu_exact(float x) {
    return 0.5f * x * (1.0f + erff(x * 0.70710678118654752f));
}

// ---------- weight prep ----------
__global__ void k_f32_to_bf16_vec4(const float* __restrict__ src, unsigned short* __restrict__ dst, int n4) {
    int i = blockIdx.x * blockDim.x + threadIdx.x;
    if (i >= n4) return;
    float4 v = ((const float4*)src)[i];
    ushort4 o;
    o.x = f2bf(v.x); o.y = f2bf(v.y); o.z = f2bf(v.z); o.w = f2bf(v.w);
    ((ushort4*)dst)[i] = o;
}

// LDS-tiled transpose: dst[c*R + r] = bf16(src[r*C + c]).  R,C multiples of 64.
// Coalesced 256B reads, coalesced 128B bf16 writes (old version did 64-way
// scattered 2B stores).
__global__ __launch_bounds__(256) void k_transpose_bf16t(const float* __restrict__ src,
                                                         unsigned short* __restrict__ dst,
                                                         int R, int C) {
    __shared__ float ls[64][65];   // +1 pad: conflict-free column reads
    int r0 = blockIdx.x * 64, c0 = blockIdx.y * 64;
    int tid = threadIdx.x;
#pragma unroll
    for (int i = 0; i < 16; ++i) {
        int idx = tid + i * 256;
        int lr = idx >> 6, lc = idx & 63;
        ls[lr][lc] = src[(size_t)(r0 + lr) * C + c0 + lc];
    }
    __syncthreads();
#pragma unroll
    for (int i = 0; i < 16; ++i) {
        int idx = tid + i * 256;
        int oc = idx >> 6, orr = idx & 63;
        dst[(size_t)(c0 + oc) * R + r0 + orr] = f2bf(ls[orr][oc]);
    }
}

// ---------- posW[l][j] = sum_k pos_emb[l][k] * W1[1536+k][j] + b1[j] ----------
__global__ __launch_bounds__(256) void k_posW(const float* __restrict__ pos_emb, const float* __restrict__ W1,
                                              const float* __restrict__ b1, float* __restrict__ posW) {
    __shared__ float pe_s[PE];
    int l = blockIdx.x, tid = threadIdx.x;
    if (tid < PE) pe_s[tid] = pos_emb[l * PE + tid];
    __syncthreads();
    for (int jj = 0; jj < 3; ++jj) {
        int j = jj * 256 + tid;
        float acc = b1[j];
        for (int k = 0; k < PE; ++k)
            acc += pe_s[k] * W1[(size_t)(2 * DIM + k) * DIM + j];
        posW[l * DIM + j] = acc;
    }
}

// ---------- pairW[p][j] = lh[p]@W1a + rh[p]@W1b ----------
__global__ __launch_bounds__(256) void k_pairW(const float* __restrict__ hs, const int* __restrict__ pairs,
                                               const float* __restrict__ W1, float* __restrict__ pairW) {
    __shared__ float lh_s[4][DIM];
    __shared__ float rh_s[4][DIM];
    int tid = threadIdx.x;
    int jc = blockIdx.x;   // 0..2
    int g  = blockIdx.y;   // 0..63
    for (int p4 = 0; p4 < 4; ++p4) {
        int p = g * 4 + p4;
        int batch = p >> 5;
        int li = pairs[p * 2 + 0];
        int ri = pairs[p * 2 + 1];
        const float* lrow = hs + ((size_t)batch * 512 + li) * DIM;
        const float* rrow = hs + ((size_t)batch * 512 + ri) * DIM;
        for (int jj = 0; jj < 3; ++jj) {
            lh_s[p4][jj * 256 + tid] = lrow[jj * 256 + tid];
            rh_s[p4][jj * 256 + tid] = rrow[jj * 256 + tid];
        }
    }
    __syncthreads();
    int j = jc * 256 + tid;
    float a0 = 0.f, a1 = 0.f, a2 = 0.f, a3 = 0.f;
    for (int k = 0; k < DIM; ++k) {
        float w1a = W1[(size_t)k * DIM + j];
        float w1b = W1[(size_t)(DIM + k) * DIM + j];
        a0 += lh_s[0][k] * w1a + rh_s[0][k] * w1b;
        a1 += lh_s[1][k] * w1a + rh_s[1][k] * w1b;
        a2 += lh_s[2][k] * w1a + rh_s[2][k] * w1b;
        a3 += lh_s[3][k] * w1a + rh_s[3][k] * w1b;
    }
    pairW[(size_t)(g * 4 + 0) * DIM + j] = a0;
    pairW[(size_t)(g * 4 + 1) * DIM + j] = a1;
    pairW[(size_t)(g * 4 + 2) * DIM + j] = a2;
    pairW[(size_t)(g * 4 + 3) * DIM + j] = a3;
}

// ---------- h1[row] = LN(gelu(pairW[p] + posW[l])) -> bf16 ----------
__global__ __launch_bounds__(256) void k_h1(const float* __restrict__ pairW, const float* __restrict__ posW,
                                            const float* __restrict__ g1, const float* __restrict__ be1,
                                            unsigned short* __restrict__ h1) {
    __shared__ float xs[DIM];
    __shared__ float red[10];
    int row = blockIdx.x, tid = threadIdx.x;
    int p = row / LSPAN, l = row % LSPAN;
    float s = 0.f, s2 = 0.f;
    for (int jj = 0; jj < 3; ++jj) {
        int j = jj * 256 + tid;
        float v = pairW[(size_t)p * DIM + j] + posW[l * DIM + j];
        float gv = gelu_exact(v);
        xs[j] = gv;
        s += gv; s2 += gv * gv;
    }
    for (int off = 32; off > 0; off >>= 1) { s += __shfl_down(s, off); s2 += __shfl_down(s2, off); }
    int w = tid >> 6, lane = tid & 63;
    if (lane == 0) { red[w] = s; red[4 + w] = s2; }
    __syncthreads();
    if (tid == 0) {
        float a = red[0] + red[1] + red[2] + red[3];
        float b = red[4] + red[5] + red[6] + red[7];
        float mu = a / DIM;
        float var = fmaxf(b / DIM - mu * mu, 0.f);
        red[8] = mu; red[9] = rsqrtf(var + 1e-12f);
    }
    __syncthreads();
    float mu = red[8], rstd = red[9];
    for (int jj = 0; jj < 3; ++jj) {
        int j = jj * 256 + tid;
        h1[(size_t)row * DIM + j] = f2bf((xs[j] - mu) * rstd * g1[j] + be1[j]);
    }
}

// ---------- row LN over 768: fp32 in -> bf16 out ----------
__global__ __launch_bounds__(256) void k_ln(const float* __restrict__ in, const float* __restrict__ gamma,
                                            const float* __restrict__ beta, unsigned short* __restrict__ out) {
    __shared__ float xs[DIM];
    __shared__ float red[10];
    int row = blockIdx.x, tid = threadIdx.x;
    float s = 0.f, s2 = 0.f;
    for (int jj = 0; jj < 3; ++jj) {
        int j = jj * 256 + tid;
        float v = in[(size_t)row * DIM + j];
        xs[j] = v;
        s += v; s2 += v * v;
    }
    for (int off = 32; off > 0; off >>= 1) { s += __shfl_down(s, off); s2 += __shfl_down(s2, off); }
    int w = tid >> 6, lane = tid & 63;
    if (lane == 0) { red[w] = s; red[4 + w] = s2; }
    __syncthreads();
    if (tid == 0) {
        float a = red[0] + red[1] + red[2] + red[3];
        float b = red[4] + red[5] + red[6] + red[7];
        float mu = a / DIM;
        float var = fmaxf(b / DIM - mu * mu, 0.f);
        red[8] = mu; red[9] = rsqrtf(var + 1e-12f);
    }
    __syncthreads();
    float mu = red[8], rstd = red[9];
    for (int jj = 0; jj < 3; ++jj) {
        int j = jj * 256 + tid;
        out[(size_t)row * DIM + j] = f2bf((xs[j] - mu) * rstd * gamma[j] + beta[j]);
    }
}

// ---------- BT-GEMM: C[M,N] = A[M,K] * B[N,K]^T  (bf16 in, fp32 acc) ----------
// EPI 1: v=gelu(v+bias[col]) store fp32. EPI 2: v+=bias[col] store bf16.
// M-panel index is XCD-chunk-swizzled (requires gridDim.x % 8 == 0; both users
// launch gridDim.x=80): each XCD owns a contiguous M-slice -> its A-panel slice
// (~1MB bf16) + full B stay L2-resident.
template <int EPI>
__global__ __launch_bounds__(256) void gemm_bt(const unsigned short* __restrict__ A,
                                               const unsigned short* __restrict__ B,
                                               const float* __restrict__ bias, void* __restrict__ Cout,
                                               int M, int N, int K, int ldc) {
    const int LDT = 136;  // LDS row stride (bf16 elems), +16B pad: conflict-free frag reads
    __shared__ unsigned short As[64 * LDT];
    __shared__ unsigned short Bs[64 * LDT];
    int tid = threadIdx.x;
    int bx = ((blockIdx.x & 7) * (gridDim.x >> 3)) + (blockIdx.x >> 3);  // XCD chunk swizzle
    int m0 = bx * 64;
    int n0 = blockIdx.y * 64;
    int w = tid >> 6, lane = tid & 63;
    int quad = lane >> 4, r16 = lane & 15;
    int wm = (w >> 1) * 32, wn = (w & 1) * 32;

    floatx4 acc[2][2] = {};

    for (int k0 = 0; k0 < K; k0 += 128) {
#pragma unroll
        for (int i = 0; i < 4; ++i) {
            int c = tid + i * 256;      // 0..1023
            int row = c >> 4;
            int kc = (c & 15) * 8;
            uint4 v = *(const uint4*)(&A[(size_t)(m0 + row) * K + k0 + kc]);
            *(uint4*)(&As[row * LDT + kc]) = v;
        }
#pragma unroll
        for (int i = 0; i < 4; ++i) {
            int c = tid + i * 256;
            int row = c >> 4;
            int kc = (c & 15) * 8;
            uint4 v = make_uint4(0u, 0u, 0u, 0u);
            if (n0 + row < N)
                v = *(const uint4*)(&B[(size_t)(n0 + row) * K + k0 + kc]);
            *(uint4*)(&Bs[row * LDT + kc]) = v;
        }
        __syncthreads();
#pragma unroll
        for (int kk = 0; kk < 4; ++kk) {
            short8 a0 = *(const short8*)(&As[(wm + 0 * 16 + r16) * LDT + kk * 32 + quad * 8]);
            short8 a1 = *(const short8*)(&As[(wm + 1 * 16 + r16) * LDT + kk * 32 + quad * 8]);
            short8 b0 = *(const short8*)(&Bs[(wn + 0 * 16 + r16) * LDT + kk * 32 + quad * 8]);
            short8 b1 = *(const short8*)(&Bs[(wn + 1 * 16 + r16) * LDT + kk * 32 + quad * 8]);
            acc[0][0] = __builtin_amdgcn_mfma_f32_16x16x32_bf16(a0, b0, acc[0][0], 0, 0, 0);
            acc[0][1] = __builtin_amdgcn_mfma_f32_16x16x32_bf16(a0, b1, acc[0][1], 0, 0, 0);
            acc[1][0] = __builtin_amdgcn_mfma_f32_16x16x32_bf16(a1, b0, acc[1][0], 0, 0, 0);
            acc[1][1] = __builtin_amdgcn_mfma_f32_16x16x32_bf16(a1, b1, acc[1][1], 0, 0, 0);
        }
        __syncthreads();
    }

#pragma unroll
    for (int mt = 0; mt < 2; ++mt)
#pragma unroll
        for (int nt = 0; nt < 2; ++nt)
#pragma unroll
            for (int r = 0; r < 4; ++r) {
                int row = m0 + wm + mt * 16 + quad * 4 + r;
                int col = n0 + wn + nt * 16 + r16;
                if (col < N) {
                    float v = acc[mt][nt][r];
                    if (EPI == 1) {
                        v = gelu_exact(v + bias[col]);
                        ((float*)Cout)[(size_t)row * ldc + col] = v;
                    } else if (EPI == 2) {
                        v += bias[col];
                        ((unsigned short*)Cout)[(size_t)row * ldc + col] = f2bf(v);
                    } else {
                        ((float*)Cout)[(size_t)row * ldc + col] = v;
                    }
                }
            }
}

// ---------- decoder GEMM: out[5120,30522] = h3[5120,128] @ Wdec[30522,128]^T ----------
// K=128 (single pass). Tile 64x128, 4 waves (2x2), each wave 32x64.
// XCD N-panel chunking: XCD x owns panels [x*30, x*30+30) -> per-XCD working set
// = its B slice (30*128 rows * 256B = 0.98MB) + all of A (1.3MB) -> L2-resident.
// A/B re-fetch (was ~1.25GB from L3/HBM at 64x64 tiles) becomes L2 hits; HBM
// traffic collapses to the compulsory 625MB output write.
#define DEC_NB  239   // ceil(30522/128)
#define DEC_MB  80    // 5120/64
#define DEC_NPX 30    // ceil(239/8) panels per XCD

__global__ __launch_bounds__(256) void gemm_dec(const unsigned short* __restrict__ A,
                                                const unsigned short* __restrict__ B,
                                                float* __restrict__ C) {
    const int LDT = 136;
    __shared__ unsigned short As[64 * LDT];
    __shared__ unsigned short Bs[128 * LDT];
    int flat = blockIdx.x;
    int xcd = flat & 7;           // consecutive blocks round-robin across XCDs
    int j = flat >> 3;
    int m = j % DEC_MB;
    int npl = j / DEC_MB;         // 0..29
    int npanel = xcd * DEC_NPX + npl;
    if (npanel >= DEC_NB) return; // 1 panel-slot idle on xcd 7
    int m0 = m * 64;
    int n0 = npanel * 128;
    int tid = threadIdx.x;
    int w = tid >> 6, lane = tid & 63;
    int quad = lane >> 4, r16 = lane & 15;
    int wm = (w >> 1) * 32, wn = (w & 1) * 64;

    // stage A: 64 rows x 128 cols (16KB)
#pragma unroll
    for (int i = 0; i < 4; ++i) {
        int c = tid + i * 256;
        int row = c >> 4, kc = (c & 15) * 8;
        *(uint4*)(&As[row * LDT + kc]) = *(const uint4*)(&A[(size_t)(m0 + row) * 128 + kc]);
    }
    // stage B: 128 rows x 128 cols (32KB). OOB rows clamped (their cols are
    // never stored, so duplicate data is harmless and avoids a buffer overrun).
#pragma unroll
    for (int i = 0; i < 8; ++i) {
        int c = tid + i * 256;
        int row = c >> 4, kc = (c & 15) * 8;
        int brow = n0 + row;
        if (brow >= VOCAB) brow = VOCAB - 1;
        *(uint4*)(&Bs[row * LDT + kc]) = *(const uint4*)(&B[(size_t)brow * 128 + kc]);
    }
    __syncthreads();

    floatx4 acc[2][4] = {};
#pragma unroll
    for (int kk = 0; kk < 4; ++kk) {
        short8 a0 = *(const short8*)(&As[(wm + 0 * 16 + r16) * LDT + kk * 32 + quad * 8]);
        short8 a1 = *(const short8*)(&As[(wm + 1 * 16 + r16) * LDT + kk * 32 + quad * 8]);
        short8 b0 = *(const short8*)(&Bs[(wn + 0 * 16 + r16) * LDT + kk * 32 + quad * 8]);
        short8 b1 = *(const short8*)(&Bs[(wn + 1 * 16 + r16) * LDT + kk * 32 + quad * 8]);
        short8 b2 = *(const short8*)(&Bs[(wn + 2 * 16 + r16) * LDT + kk * 32 + quad * 8]);
        short8 b3 = *(const short8*)(&Bs[(wn + 3 * 16 + r16) * LDT + kk * 32 + quad * 8]);
        acc[0][0] = __builtin_amdgcn_mfma_f32_16x16x32_bf16(a0, b0, acc[0][0], 0, 0, 0);
        acc[0][1] = __builtin_amdgcn_mfma_f32_16x16x32_bf16(a0, b1, acc[0][1], 0, 0, 0);
        acc[0][2] = __builtin_amdgcn_mfma_f32_16x16x32_bf16(a0, b2, acc[0][2], 0, 0, 0);
        acc[0][3] = __builtin_amdgcn_mfma_f32_16x16x32_bf16(a0, b3, acc[0][3], 0, 0, 0);
        acc[1][0] = __builtin_amdgcn_mfma_f32_16x16x32_bf16(a1, b0, acc[1][0], 0, 0, 0);
        acc[1][1] = __builtin_amdgcn_mfma_f32_16x16x32_bf16(a1, b1, acc[1][1], 0, 0, 0);
        acc[1][2] = __builtin_amdgcn_mfma_f32_16x16x32_bf16(a1, b2, acc[1][2], 0, 0, 0);
        acc[1][3] = __builtin_amdgcn_mfma_f32_16x16x32_bf16(a1, b3, acc[1][3], 0, 0, 0);
    }

#pragma unroll
    for (int mt = 0; mt < 2; ++mt)
#pragma unroll
        for (int nt = 0; nt < 4; ++nt)
#pragma unroll
            for (int r = 0; r < 4; ++r) {
                int row = m0 + wm + mt * 16 + quad * 4 + r;
                int col = n0 + wn + nt * 16 + r16;
                if (col < VOCAB)
                    C[(size_t)row * VOCAB + col] = acc[mt][nt][r];
            }
}

extern "C" void kernel_launch(void* const* d_in, const int* in_sizes, int n_in,
                              void* d_out, int out_size, void* d_ws, size_t ws_size,
                              hipStream_t stream) {
    const float* hs      = (const float*)d_in[0];
    const int*   pairs   = (const int*)d_in[1];
    const float* pos_emb = (const float*)d_in[2];
    const float* W1      = (const float*)d_in[3];
    const float* b1      = (const float*)d_in[4];
    const float* g1      = (const float*)d_in[5];
    const float* be1     = (const float*)d_in[6];
    const float* W2      = (const float*)d_in[7];
    const float* b2      = (const float*)d_in[8];
    const float* g2      = (const float*)d_in[9];
    const float* be2     = (const float*)d_in[10];
    const float* Wp      = (const float*)d_in[11];
    const float* bp      = (const float*)d_in[12];
    const float* Wdec    = (const float*)d_in[13];
    float* out = (float*)d_out;

    char* ws = (char*)d_ws;
    float*          posW  = (float*)(ws + 0);                 //  20*768*4   = 61440
    float*          pairW = (float*)(ws + 61440);             // 256*768*4   = 786432
    unsigned short* h1    = (unsigned short*)(ws + 847872);   // 5120*768*2  = 7864320
    unsigned short* W2T   = (unsigned short*)(ws + 8712192);  // 768*768*2   = 1179648
    float*          y     = (float*)(ws + 9891840);           // 5120*768*4  = 15728640
    unsigned short* h2    = (unsigned short*)(ws + 25620480); // 5120*768*2  = 7864320
    unsigned short* WpT   = (unsigned short*)(ws + 33484800); // 128*768*2   = 196608
    unsigned short* h3    = (unsigned short*)(ws + 33681408); // 5120*128*2  = 1310720
    unsigned short* WdecB = (unsigned short*)(ws + 34992128); // 30522*128*2 = 7813632
    // total ws usage: 42805760 bytes

    // weight prep
    int n4 = (VOCAB * EMB) / 4;  // 976704
    k_f32_to_bf16_vec4<<<(n4 + 255) / 256, 256, 0, stream>>>(Wdec, WdecB, n4);
    k_transpose_bf16t<<<dim3(DIM / 64, DIM / 64), 256, 0, stream>>>(W2, W2T, DIM, DIM);
    k_transpose_bf16t<<<dim3(DIM / 64, EMB / 64), 256, 0, stream>>>(Wp, WpT, DIM, EMB);

    // layer-1 structural decomposition
    k_posW<<<LSPAN, 256, 0, stream>>>(pos_emb, W1, b1, posW);
    k_pairW<<<dim3(3, 64), 256, 0, stream>>>(hs, pairs, W1, pairW);
    k_h1<<<ROWS, 256, 0, stream>>>(pairW, posW, g1, be1, h1);

    // layer 2: y = gelu(h1@W2 + b2); h2 = LN(y)
    gemm_bt<1><<<dim3(ROWS / 64, DIM / 64), 256, 0, stream>>>(h1, W2T, b2, y, ROWS, DIM, DIM, DIM);
    k_ln<<<ROWS, 256, 0, stream>>>(y, g2, be2, h2);

    // projection: h3 = h2@Wp + bp
    gemm_bt<2><<<dim3(ROWS / 64, EMB / 64), 256, 0, stream>>>(h2, WpT, bp, h3, ROWS, EMB, DIM, EMB);

    // decoder: out = h3 @ Wdec^T  (XCD N-panel-chunked, 64x128 tiles)
    gemm_dec<<<8 * DEC_NPX * DEC_MB, 256, 0, stream>>>(h3, WdecB, out);
}

// Round 2
// 915.686 us; speedup vs baseline: 1.0712x; 1.0598x over previous
//
#include <hip/hip_runtime.h>
#include <math.h>

#define DIM    768
#define PE     200
#define LSPAN  20
#define NPAIRS 256
#define ROWS   5120
#define EMB    128
#define VOCAB  30522

typedef __attribute__((ext_vector_type(8))) short short8;
typedef __attribute__((ext_vector_type(4))) float floatx4;

__device__ inline unsigned short f2bf(float f) {
    union { float f; unsigned int u; } v; v.f = f;
    unsigned int r = v.u + 0x7fffu + ((v.u >> 16) & 1u);
    return (unsigned short)(r >> 16);
}
__device__ inline float gelu_exact(float x) {
    return 0.5f * x * (1.0f + erff(x * 0.70710678118654752f));
}

// ---------- merged weight prep: Wdec->bf16 | W2^T | Wp^T | posW ----------
// Block ranges: [0,3816) conversion, [3816,3960) W2T tiles (12x12),
// [3960,3984) WpT tiles (12x2), [3984,4004) posW rows.
#define PREP_CONV 3816
#define PREP_T1   3960
#define PREP_T2   3984
#define PREP_TOT  4004

__global__ __launch_bounds__(256) void k_prep(const float* __restrict__ Wdec, unsigned short* __restrict__ WdecB,
                                              const float* __restrict__ W2, unsigned short* __restrict__ W2T,
                                              const float* __restrict__ Wp, unsigned short* __restrict__ WpT,
                                              const float* __restrict__ pos_emb, const float* __restrict__ W1,
                                              const float* __restrict__ b1, float* __restrict__ posW) {
    __shared__ float ls[64][65];   // transpose tile (+1 pad); reused as pe_s for posW
    int b = blockIdx.x, tid = threadIdx.x;
    if (b < PREP_CONV) {
        int i = b * 256 + tid;
        if (i < (VOCAB * EMB) / 4) {
            float4 v = ((const float4*)Wdec)[i];
            ushort4 o;
            o.x = f2bf(v.x); o.y = f2bf(v.y); o.z = f2bf(v.z); o.w = f2bf(v.w);
            ((ushort4*)WdecB)[i] = o;
        }
        return;
    }
    if (b < PREP_T2) {  // LDS-tiled transpose: dst[c*R+r] = bf16(src[r*C+c])
        const float* src; unsigned short* dst; int C, R, tr, tc;
        if (b < PREP_T1) { int bb = b - PREP_CONV; src = W2; dst = W2T; R = DIM; C = DIM; tr = bb / 12; tc = bb % 12; }
        else             { int bb = b - PREP_T1;   src = Wp; dst = WpT; R = DIM; C = EMB; tr = bb / 2;  tc = bb % 2;  }
        int r0 = tr * 64, c0 = tc * 64;
#pragma unroll
        for (int i = 0; i < 16; ++i) {
            int idx = tid + i * 256;
            int lr = idx >> 6, lc = idx & 63;
            ls[lr][lc] = src[(size_t)(r0 + lr) * C + c0 + lc];
        }
        __syncthreads();
#pragma unroll
        for (int i = 0; i < 16; ++i) {
            int idx = tid + i * 256;
            int oc = idx >> 6, orr = idx & 63;
            dst[(size_t)(c0 + oc) * R + r0 + orr] = f2bf(ls[orr][oc]);
        }
        return;
    }
    // posW[l][j] = sum_k pos_emb[l][k] * W1[1536+k][j] + b1[j]
    int l = b - PREP_T2;
    float* pe_s = &ls[0][0];
    if (tid < PE) pe_s[tid] = pos_emb[l * PE + tid];
    __syncthreads();
    for (int jj = 0; jj < 3; ++jj) {
        int j = jj * 256 + tid;
        float acc = b1[j];
        for (int k = 0; k < PE; ++k)
            acc += pe_s[k] * W1[(size_t)(2 * DIM + k) * DIM + j];
        posW[l * DIM + j] = acc;
    }
}

// ---------- pairW[p][j] = lh[p]@W1a + rh[p]@W1b ----------
__global__ __launch_bounds__(256) void k_pairW(const float* __restrict__ hs, const int* __restrict__ pairs,
                                               const float* __restrict__ W1, float* __restrict__ pairW) {
    __shared__ float lh_s[4][DIM];
    __shared__ float rh_s[4][DIM];
    int tid = threadIdx.x;
    int jc = blockIdx.x;   // 0..2
    int g  = blockIdx.y;   // 0..63
    for (int p4 = 0; p4 < 4; ++p4) {
        int p = g * 4 + p4;
        int batch = p >> 5;
        int li = pairs[p * 2 + 0];
        int ri = pairs[p * 2 + 1];
        const float* lrow = hs + ((size_t)batch * 512 + li) * DIM;
        const float* rrow = hs + ((size_t)batch * 512 + ri) * DIM;
        for (int jj = 0; jj < 3; ++jj) {
            lh_s[p4][jj * 256 + tid] = lrow[jj * 256 + tid];
            rh_s[p4][jj * 256 + tid] = rrow[jj * 256 + tid];
        }
    }
    __syncthreads();
    int j = jc * 256 + tid;
    float a0 = 0.f, a1 = 0.f, a2 = 0.f, a3 = 0.f;
    for (int k = 0; k < DIM; ++k) {
        float w1a = W1[(size_t)k * DIM + j];
        float w1b = W1[(size_t)(DIM + k) * DIM + j];
        a0 += lh_s[0][k] * w1a + rh_s[0][k] * w1b;
        a1 += lh_s[1][k] * w1a + rh_s[1][k] * w1b;
        a2 += lh_s[2][k] * w1a + rh_s[2][k] * w1b;
        a3 += lh_s[3][k] * w1a + rh_s[3][k] * w1b;
    }
    pairW[(size_t)(g * 4 + 0) * DIM + j] = a0;
    pairW[(size_t)(g * 4 + 1) * DIM + j] = a1;
    pairW[(size_t)(g * 4 + 2) * DIM + j] = a2;
    pairW[(size_t)(g * 4 + 3) * DIM + j] = a3;
}

// ---------- h1[row] = LN(gelu(pairW[p] + posW[l])) -> bf16 ----------
__global__ __launch_bounds__(256) void k_h1(const float* __restrict__ pairW, const float* __restrict__ posW,
                                            const float* __restrict__ g1, const float* __restrict__ be1,
                                            unsigned short* __restrict__ h1) {
    __shared__ float xs[DIM];
    __shared__ float red[10];
    int row = blockIdx.x, tid = threadIdx.x;
    int p = row / LSPAN, l = row % LSPAN;
    float s = 0.f, s2 = 0.f;
    for (int jj = 0; jj < 3; ++jj) {
        int j = jj * 256 + tid;
        float v = pairW[(size_t)p * DIM + j] + posW[l * DIM + j];
        float gv = gelu_exact(v);
        xs[j] = gv;
        s += gv; s2 += gv * gv;
    }
    for (int off = 32; off > 0; off >>= 1) { s += __shfl_down(s, off); s2 += __shfl_down(s2, off); }
    int w = tid >> 6, lane = tid & 63;
    if (lane == 0) { red[w] = s; red[4 + w] = s2; }
    __syncthreads();
    if (tid == 0) {
        float a = red[0] + red[1] + red[2] + red[3];
        float b = red[4] + red[5] + red[6] + red[7];
        float mu = a / DIM;
        float var = fmaxf(b / DIM - mu * mu, 0.f);
        red[8] = mu; red[9] = rsqrtf(var + 1e-12f);
    }
    __syncthreads();
    float mu = red[8], rstd = red[9];
    for (int jj = 0; jj < 3; ++jj) {
        int j = jj * 256 + tid;
        h1[(size_t)row * DIM + j] = f2bf((xs[j] - mu) * rstd * g1[j] + be1[j]);
    }
}

// ---------- row LN over 768: fp32 in -> bf16 out ----------
__global__ __launch_bounds__(256) void k_ln(const float* __restrict__ in, const float* __restrict__ gamma,
                                            const float* __restrict__ beta, unsigned short* __restrict__ out) {
    __shared__ float xs[DIM];
    __shared__ float red[10];
    int row = blockIdx.x, tid = threadIdx.x;
    float s = 0.f, s2 = 0.f;
    for (int jj = 0; jj < 3; ++jj) {
        int j = jj * 256 + tid;
        float v = in[(size_t)row * DIM + j];
        xs[j] = v;
        s += v; s2 += v * v;
    }
    for (int off = 32; off > 0; off >>= 1) { s += __shfl_down(s, off); s2 += __shfl_down(s2, off); }
    int w = tid >> 6, lane = tid & 63;
    if (lane == 0) { red[w] = s; red[4 + w] = s2; }
    __syncthreads();
    if (tid == 0) {
        float a = red[0] + red[1] + red[2] + red[3];
        float b = red[4] + red[5] + red[6] + red[7];
        float mu = a / DIM;
        float var = fmaxf(b / DIM - mu * mu, 0.f);
        red[8] = mu; red[9] = rsqrtf(var + 1e-12f);
    }
    __syncthreads();
    float mu = red[8], rstd = red[9];
    for (int jj = 0; jj < 3; ++jj) {
        int j = jj * 256 + tid;
        out[(size_t)row * DIM + j] = f2bf((xs[j] - mu) * rstd * gamma[j] + beta[j]);
    }
}

// ---------- BT-GEMM: C[M,N] = A[M,K] * B[N,K]^T  (bf16 in, fp32 acc) ----------
// EPI 1: v=gelu(v+bias[col]) store fp32. EPI 2: v+=bias[col] store bf16.
// XCD chunk swizzle on M-panel (gridDim.x % 8 == 0 for both users).
template <int EPI>
__global__ __launch_bounds__(256) void gemm_bt(const unsigned short* __restrict__ A,
                                               const unsigned short* __restrict__ B,
                                               const float* __restrict__ bias, void* __restrict__ Cout,
                                               int M, int N, int K, int ldc) {
    const int LDT = 136;  // LDS row stride (bf16 elems), +16B pad: conflict-free frag reads
    __shared__ unsigned short As[64 * LDT];
    __shared__ unsigned short Bs[64 * LDT];
    int tid = threadIdx.x;
    int bx = ((blockIdx.x & 7) * (gridDim.x >> 3)) + (blockIdx.x >> 3);  // XCD chunk swizzle
    int m0 = bx * 64;
    int n0 = blockIdx.y * 64;
    int w = tid >> 6, lane = tid & 63;
    int quad = lane >> 4, r16 = lane & 15;
    int wm = (w >> 1) * 32, wn = (w & 1) * 32;

    floatx4 acc[2][2] = {};

    for (int k0 = 0; k0 < K; k0 += 128) {
#pragma unroll
        for (int i = 0; i < 4; ++i) {
            int c = tid + i * 256;      // 0..1023
            int row = c >> 4;
            int kc = (c & 15) * 8;
            uint4 v = *(const uint4*)(&A[(size_t)(m0 + row) * K + k0 + kc]);
            *(uint4*)(&As[row * LDT + kc]) = v;
        }
#pragma unroll
        for (int i = 0; i < 4; ++i) {
            int c = tid + i * 256;
            int row = c >> 4;
            int kc = (c & 15) * 8;
            uint4 v = make_uint4(0u, 0u, 0u, 0u);
            if (n0 + row < N)
                v = *(const uint4*)(&B[(size_t)(n0 + row) * K + k0 + kc]);
            *(uint4*)(&Bs[row * LDT + kc]) = v;
        }
        __syncthreads();
#pragma unroll
        for (int kk = 0; kk < 4; ++kk) {
            short8 a0 = *(const short8*)(&As[(wm + 0 * 16 + r16) * LDT + kk * 32 + quad * 8]);
            short8 a1 = *(const short8*)(&As[(wm + 1 * 16 + r16) * LDT + kk * 32 + quad * 8]);
            short8 b0 = *(const short8*)(&Bs[(wn + 0 * 16 + r16) * LDT + kk * 32 + quad * 8]);
            short8 b1 = *(const short8*)(&Bs[(wn + 1 * 16 + r16) * LDT + kk * 32 + quad * 8]);
            acc[0][0] = __builtin_amdgcn_mfma_f32_16x16x32_bf16(a0, b0, acc[0][0], 0, 0, 0);
            acc[0][1] = __builtin_amdgcn_mfma_f32_16x16x32_bf16(a0, b1, acc[0][1], 0, 0, 0);
            acc[1][0] = __builtin_amdgcn_mfma_f32_16x16x32_bf16(a1, b0, acc[1][0], 0, 0, 0);
            acc[1][1] = __builtin_amdgcn_mfma_f32_16x16x32_bf16(a1, b1, acc[1][1], 0, 0, 0);
        }
        __syncthreads();
    }

#pragma unroll
    for (int mt = 0; mt < 2; ++mt)
#pragma unroll
        for (int nt = 0; nt < 2; ++nt)
#pragma unroll
            for (int r = 0; r < 4; ++r) {
                int row = m0 + wm + mt * 16 + quad * 4 + r;
                int col = n0 + wn + nt * 16 + r16;
                if (col < N) {
                    float v = acc[mt][nt][r];
                    if (EPI == 1) {
                        v = gelu_exact(v + bias[col]);
                        ((float*)Cout)[(size_t)row * ldc + col] = v;
                    } else if (EPI == 2) {
                        v += bias[col];
                        ((unsigned short*)Cout)[(size_t)row * ldc + col] = f2bf(v);
                    } else {
                        ((float*)Cout)[(size_t)row * ldc + col] = v;
                    }
                }
            }
}

// ---------- decoder GEMM: out[5120,30522] = h3[5120,128] @ Wdec[30522,128]^T ----------
// K=128 single pass. B-resident M-loop: each block stages its 128-col B panel
// ONCE, then sweeps 8 M-tiles {stage A, barrier, 32 MFMA, barrier, write}.
// vs round-1: 19200 blocks x (48KB stage + 2 barriers) per 32KB written
//          -> 2400 blocks; B-staging cut 8x, L2 reads 940->~380MB, half the
//             per-output-tile barrier/stage overhead. XCD N-panel chunking kept:
// XCD x owns panels [x*30, x*30+30): B slice 0.98MB + A 1.31MB L2-resident.
#define DEC_NB   239   // ceil(30522/128)
#define DEC_NPX  30    // panels per XCD
#define DEC_MPER 8     // M-tiles per block
#define DEC_MGRP 10    // 80 / DEC_MPER

__global__ __launch_bounds__(256) void gemm_dec(const unsigned short* __restrict__ A,
                                                const unsigned short* __restrict__ B,
                                                float* __restrict__ C) {
    const int LDT = 136;
    __shared__ unsigned short As[64 * LDT];
    __shared__ unsigned short Bs[128 * LDT];
    int flat = blockIdx.x;
    int xcd = flat & 7;           // consecutive blocks round-robin across XCDs
    int j = flat >> 3;            // 0..299
    int npl = j % DEC_NPX;
    int mg  = j / DEC_NPX;        // 0..9
    int npanel = xcd * DEC_NPX + npl;
    if (npanel >= DEC_NB) return; // 10 idle blocks on xcd 7
    int n0 = npanel * 128;
    int tid = threadIdx.x;
    int w = tid >> 6, lane = tid & 63;
    int quad = lane >> 4, r16 = lane & 15;
    int wm = (w >> 1) * 32, wn = (w & 1) * 64;

    // stage B once: 128 rows x 128 cols (32KB). OOB rows clamped (cols never stored).
#pragma unroll
    for (int i = 0; i < 8; ++i) {
        int c = tid + i * 256;
        int row = c >> 4, kc = (c & 15) * 8;
        int brow = n0 + row;
        if (brow >= VOCAB) brow = VOCAB - 1;
        *(uint4*)(&Bs[row * LDT + kc]) = *(const uint4*)(&B[(size_t)brow * 128 + kc]);
    }

    for (int t = 0; t < DEC_MPER; ++t) {
        int m0 = (mg * DEC_MPER + t) * 64;
#pragma unroll
        for (int i = 0; i < 4; ++i) {
            int c = tid + i * 256;
            int row = c >> 4, kc = (c & 15) * 8;
            *(uint4*)(&As[row * LDT + kc]) = *(const uint4*)(&A[(size_t)(m0 + row) * 128 + kc]);
        }
        __syncthreads();   // As ready (and Bs on t=0)

        floatx4 acc[2][4] = {};
#pragma unroll
        for (int kk = 0; kk < 4; ++kk) {
            short8 a0 = *(const short8*)(&As[(wm + 0 * 16 + r16) * LDT + kk * 32 + quad * 8]);
            short8 a1 = *(const short8*)(&As[(wm + 1 * 16 + r16) * LDT + kk * 32 + quad * 8]);
            short8 b0 = *(const short8*)(&Bs[(wn + 0 * 16 + r16) * LDT + kk * 32 + quad * 8]);
            short8 b1 = *(const short8*)(&Bs[(wn + 1 * 16 + r16) * LDT + kk * 32 + quad * 8]);
            short8 b2 = *(const short8*)(&Bs[(wn + 2 * 16 + r16) * LDT + kk * 32 + quad * 8]);
            short8 b3 = *(const short8*)(&Bs[(wn + 3 * 16 + r16) * LDT + kk * 32 + quad * 8]);
            acc[0][0] = __builtin_amdgcn_mfma_f32_16x16x32_bf16(a0, b0, acc[0][0], 0, 0, 0);
            acc[0][1] = __builtin_amdgcn_mfma_f32_16x16x32_bf16(a0, b1, acc[0][1], 0, 0, 0);
            acc[0][2] = __builtin_amdgcn_mfma_f32_16x16x32_bf16(a0, b2, acc[0][2], 0, 0, 0);
            acc[0][3] = __builtin_amdgcn_mfma_f32_16x16x32_bf16(a0, b3, acc[0][3], 0, 0, 0);
            acc[1][0] = __builtin_amdgcn_mfma_f32_16x16x32_bf16(a1, b0, acc[1][0], 0, 0, 0);
            acc[1][1] = __builtin_amdgcn_mfma_f32_16x16x32_bf16(a1, b1, acc[1][1], 0, 0, 0);
            acc[1][2] = __builtin_amdgcn_mfma_f32_16x16x32_bf16(a1, b2, acc[1][2], 0, 0, 0);
            acc[1][3] = __builtin_amdgcn_mfma_f32_16x16x32_bf16(a1, b3, acc[1][3], 0, 0, 0);
        }
        __syncthreads();   // MFMA reads done before next As overwrite

#pragma unroll
        for (int mt = 0; mt < 2; ++mt)
#pragma unroll
            for (int nt = 0; nt < 4; ++nt)
#pragma unroll
                for (int r = 0; r < 4; ++r) {
                    int row = m0 + wm + mt * 16 + quad * 4 + r;
                    int col = n0 + wn + nt * 16 + r16;
                    if (col < VOCAB)
                        C[(size_t)row * VOCAB + col] = acc[mt][nt][r];
                }
    }
}

extern "C" void kernel_launch(void* const* d_in, const int* in_sizes, int n_in,
                              void* d_out, int out_size, void* d_ws, size_t ws_size,
                              hipStream_t stream) {
    const float* hs      = (const float*)d_in[0];
    const int*   pairs   = (const int*)d_in[1];
    const float* pos_emb = (const float*)d_in[2];
    const float* W1      = (const float*)d_in[3];
    const float* b1      = (const float*)d_in[4];
    const float* g1      = (const float*)d_in[5];
    const float* be1     = (const float*)d_in[6];
    const float* W2      = (const float*)d_in[7];
    const float* b2      = (const float*)d_in[8];
    const float* g2      = (const float*)d_in[9];
    const float* be2     = (const float*)d_in[10];
    const float* Wp      = (const float*)d_in[11];
    const float* bp      = (const float*)d_in[12];
    const float* Wdec    = (const float*)d_in[13];
    float* out = (float*)d_out;

    char* ws = (char*)d_ws;
    float*          posW  = (float*)(ws + 0);                 //  20*768*4   = 61440
    float*          pairW = (float*)(ws + 61440);             // 256*768*4   = 786432
    unsigned short* h1    = (unsigned short*)(ws + 847872);   // 5120*768*2  = 7864320
    unsigned short* W2T   = (unsigned short*)(ws + 8712192);  // 768*768*2   = 1179648
    float*          y     = (float*)(ws + 9891840);           // 5120*768*4  = 15728640
    unsigned short* h2    = (unsigned short*)(ws + 25620480); // 5120*768*2  = 7864320
    unsigned short* WpT   = (unsigned short*)(ws + 33484800); // 128*768*2   = 196608
    unsigned short* h3    = (unsigned short*)(ws + 33681408); // 5120*128*2  = 1310720
    unsigned short* WdecB = (unsigned short*)(ws + 34992128); // 30522*128*2 = 7813632
    // total ws usage: 42805760 bytes

    // merged weight prep + posW (1 launch, was 4)
    k_prep<<<PREP_TOT, 256, 0, stream>>>(Wdec, WdecB, W2, W2T, Wp, WpT, pos_emb, W1, b1, posW);

    // layer-1 structural decomposition
    k_pairW<<<dim3(3, 64), 256, 0, stream>>>(hs, pairs, W1, pairW);
    k_h1<<<ROWS, 256, 0, stream>>>(pairW, posW, g1, be1, h1);

    // layer 2: y = gelu(h1@W2 + b2); h2 = LN(y)
    gemm_bt<1><<<dim3(ROWS / 64, DIM / 64), 256, 0, stream>>>(h1, W2T, b2, y, ROWS, DIM, DIM, DIM);
    k_ln<<<ROWS, 256, 0, stream>>>(y, g2, be2, h2);

    // projection: h3 = h2@Wp + bp
    gemm_bt<2><<<dim3(ROWS / 64, EMB / 64), 256, 0, stream>>>(h2, WpT, bp, h3, ROWS, EMB, DIM, EMB);

    // decoder: out = h3 @ Wdec^T  (B-resident M-loop, XCD N-panel-chunked)
    gemm_dec<<<8 * DEC_NPX * DEC_MGRP, 256, 0, stream>>>(h3, WdecB, out);
}